// Round 1
// baseline (12755.070 us; speedup 1.0000x reference)
//
#include <hip/hip_runtime.h>
#include <hip/hip_bf16.h>
#include <stdint.h>

// DH-SNN forward: fused persistent-scan implementation.
// Phase 0 (parallel prep): x -> bf16 [T][B][704]; Wx -> bf16 [4096][704]; Ws^T -> f32 [1024][4096].
// Phase 1 (persistent, 256 WGs = 1/CU): per step t:
//   MFMA x_t @ Wx^T (overlapped with grid barrier wait) + exact fp32 spike-gather of Ws^T rows
//   -> branch/soma update in registers -> spike bitmask exchange -> readout+softmax in wave0 regs.

typedef short short8 __attribute__((ext_vector_type(8)));
typedef float f32x4 __attribute__((ext_vector_type(4)));

#define T_STEPS 250
#define BATCH   128
#define HID     1024
#define NCOL    4096      // HID*BRANCH
#define IND     700
#define ISZ     1724
#define KPAD    704
#define OUTD    20
#define NWG     256
#define WGT     256

// ws layout (bytes)
#define O_CNT   0
#define O_MASK  256              // uint64[2][128][16] = 32768 B
#define O_WST   33024            // f32 [1024][4096] = 16777216 B
#define O_WXH   16810240         // bf16 [4096][704] = 5767168 B
#define O_XH    22577408         // bf16 [250][128][704] = 45056000 B  (end ~67.6 MB)

__device__ __forceinline__ float sigmoidf(float x) { return 1.0f / (1.0f + expf(-x)); }

__global__ void prep_x(const float* __restrict__ x, __hip_bfloat16* __restrict__ Xh) {
    const int total = T_STEPS * BATCH * KPAD;
    for (int idx = blockIdx.x * blockDim.x + threadIdx.x; idx < total; idx += gridDim.x * blockDim.x) {
        int k = idx % KPAD;
        int tb = idx / KPAD;
        int b = tb % BATCH;
        int t = tb / BATCH;
        float v = (k < IND) ? x[((long)b * T_STEPS + t) * IND + k] : 0.0f;
        Xh[idx] = __float2bfloat16(v);
    }
}

__global__ void prep_w(const float* __restrict__ W, __hip_bfloat16* __restrict__ Wxh,
                       unsigned* __restrict__ cnt) {
    if (blockIdx.x == 0 && threadIdx.x == 0) *cnt = 0u;   // barrier counter reset (every launch)
    const int total = NCOL * KPAD;
    for (int idx = blockIdx.x * blockDim.x + threadIdx.x; idx < total; idx += gridDim.x * blockDim.x) {
        int k = idx % KPAD;
        int n = idx / KPAD;
        float v = (k < IND) ? W[(long)n * ISZ + k] : 0.0f;
        Wxh[idx] = __float2bfloat16(v);
    }
}

// Wst[h][n] = W[n][700+h]   (tiled transpose)
__global__ __launch_bounds__(256) void prep_t(const float* __restrict__ W, float* __restrict__ Wst) {
    __shared__ float tile[32][33];
    const int h0 = blockIdx.x * 32, n0 = blockIdx.y * 32;
    const int tx = threadIdx.x, ty = threadIdx.y;  // (32,8)
    #pragma unroll
    for (int j = 0; j < 32; j += 8)
        tile[ty + j][tx] = W[(long)(n0 + ty + j) * ISZ + IND + h0 + tx];
    __syncthreads();
    #pragma unroll
    for (int j = 0; j < 32; j += 8)
        Wst[(long)(h0 + ty + j) * NCOL + n0 + tx] = tile[tx][ty + j];
}

__global__ __launch_bounds__(256, 1) void snn_scan(
    const __hip_bfloat16* __restrict__ Xh, const __hip_bfloat16* __restrict__ Wxh,
    const float* __restrict__ Wst, uint64_t* __restrict__ masks, unsigned* __restrict__ cnt,
    const float* __restrict__ bvec, const float* __restrict__ tau_m, const float* __restrict__ tau_n,
    const float* __restrict__ Wr, const float* __restrict__ brv, const float* __restrict__ tau_r,
    const float* __restrict__ mem0, float* __restrict__ out)
{
    __shared__ __hip_bfloat16 Bp[32 * 712];   // Wx^T panel: [32 cols][704 k], pad 712 vs bank conflicts
    __shared__ float curL[64 * 36];           // C exchange [64 rows][32 cols], pad 36

    const int wg    = blockIdx.x;     // 0..255
    const int w     = wg & 127;       // column group: cols [w*32, w*32+32) = neurons [w*8, w*8+8)
    const int bhalf = wg >> 7;        // row split: batches [0,64) or [64,128)
    const int bbase = bhalf * 64;
    const int c0    = w * 32;
    const int i0    = w * 8;
    const int tid   = threadIdx.x;
    const int lane  = tid & 63, wid = tid >> 6;

    // stage B panel into LDS (persistent for all 250 steps)
    for (int idx = tid; idx < 32 * KPAD; idx += WGT) {
        int col = idx / KPAD, k = idx % KPAD;
        Bp[col * 712 + k] = Wxh[(long)(c0 + col) * KPAD + k];
    }

    // per-thread state: 2 neurons x 4 branches, one batch row
    const int r  = tid >> 2;          // local batch row 0..63
    const int nq = tid & 3;
    const int b  = bbase + r;         // global batch
    float dn[8], beta[8], bias[8], mem[2], alph[2], spkf[2];
    #pragma unroll
    for (int m = 0; m < 2; ++m) {
        int i = i0 + nq * 2 + m;
        alph[m] = sigmoidf(tau_m[i]);
        mem[m]  = mem0[b * HID + i];
        spkf[m] = 0.0f;
        #pragma unroll
        for (int j = 0; j < 4; ++j) {
            beta[m * 4 + j] = sigmoidf(tau_n[i * 4 + j]);
            bias[m * 4 + j] = bvec[i * 4 + j];
            dn[m * 4 + j]   = 0.0f;
        }
    }

    // readout state (WG b<128 handles batch wg; lanes 0..19 of wave 0)
    const bool isRO = (wg < BATCH) && (tid < 32);
    float r_alpha = 0.f, r_bias = 0.f, r_rmem = 0.f, r_acc = 0.f;
    const float* WrRow = Wr;
    if (isRO) {
        int o = (tid < OUTD) ? tid : 0;
        r_alpha = sigmoidf(tau_r[o]);
        r_bias  = brv[o];
        WrRow   = Wr + o * HID;
    }

    // GEMM addressing
    const int arowL = wid * 16 + (lane & 15);    // local output row 0..63
    const int kb8   = (lane >> 4) * 8;           // k-subblock within K=32 step
    const int colA  = lane & 15;                 // fragment column
    const __hip_bfloat16* Arow = Xh + ((long)bbase + arowL) * KPAD + kb8;

    __syncthreads();

    for (int t = 0; t <= T_STEPS; ++t) {
        const bool doUpd = (t < T_STEPS);
        f32x4 acc0 = {0.f, 0.f, 0.f, 0.f}, acc1 = {0.f, 0.f, 0.f, 0.f};

        // ---- 1. MFMA x_t @ Wx^T (issued BEFORE the barrier wait -> overlaps spin) ----
        if (doUpd) {
            const __hip_bfloat16* Ab = Arow + (long)t * BATCH * KPAD;
            #pragma unroll
            for (int k0 = 0; k0 < KPAD; k0 += 32) {
                short8 af = *(const short8*)(Ab + k0);
                short8 b0 = *(const short8*)(&Bp[(colA) * 712 + k0 + kb8]);
                short8 b1 = *(const short8*)(&Bp[(16 + colA) * 712 + k0 + kb8]);
                acc0 = __builtin_amdgcn_mfma_f32_16x16x32_bf16(af, b0, acc0, 0, 0, 0);
                acc1 = __builtin_amdgcn_mfma_f32_16x16x32_bf16(af, b1, acc1, 0, 0, 0);
            }
        }

        // ---- 2. wait: spikes[t-1] globally visible ----
        if (t > 0) {
            const unsigned target = (unsigned)t * NWG;
            if (tid == 0) {
                while (__hip_atomic_load(cnt, __ATOMIC_ACQUIRE, __HIP_MEMORY_SCOPE_AGENT) < target)
                    __builtin_amdgcn_s_sleep(1);
            }
            __syncthreads();
            __threadfence();   // invalidate L1 so mask reads are fresh
        }

        // ---- 3. C fragments -> LDS ----
        if (doUpd) {
            const int crow = wid * 16 + (lane >> 4) * 4;
            #pragma unroll
            for (int j = 0; j < 4; ++j) {
                curL[(crow + j) * 36 + colA]      = acc0[j];
                curL[(crow + j) * 36 + 16 + colA] = acc1[j];
            }
            __syncthreads();
        }

        // ---- 4. recurrent gather (exact fp32) + readout of step t-1 ----
        f32x4 rec0 = {0.f, 0.f, 0.f, 0.f}, rec1 = {0.f, 0.f, 0.f, 0.f};
        if (t > 0) {
            if (doUpd) {
                const uint64_t* mrow = masks + ((size_t)((t - 1) & 1)) * 2048 + (size_t)b * 16;
                const float* Wb = Wst + c0 + nq * 8;
                for (int q = 0; q < 16; ++q) {
                    uint64_t mword = mrow[q];
                    while (mword) {
                        int h = (q << 6) + __builtin_ctzll(mword);
                        mword &= mword - 1;
                        const f32x4* wv = (const f32x4*)(Wb + (long)h * NCOL);
                        rec0 += wv[0];
                        rec1 += wv[1];
                    }
                }
            }
            if (isRO) {  // readout for step s = t-1 (needs all spikes of batch wg)
                const uint64_t* mrow = masks + ((size_t)((t - 1) & 1)) * 2048 + (size_t)wg * 16;
                float rsum = 0.f;
                for (int q = 0; q < 16; ++q) {
                    uint64_t mword = mrow[q];
                    while (mword) {
                        int h = (q << 6) + __builtin_ctzll(mword);
                        mword &= mword - 1;
                        rsum += WrRow[h];
                    }
                }
                r_rmem = r_alpha * r_rmem + (1.0f - r_alpha) * (rsum + r_bias);
                float v = (tid < OUTD) ? r_rmem : -__builtin_inff();
                #pragma unroll
                for (int d = 16; d > 0; d >>= 1) v = fmaxf(v, __shfl_xor(v, d, 32));
                float e = (tid < OUTD) ? expf(r_rmem - v) : 0.f;
                float s = e;
                #pragma unroll
                for (int d = 16; d > 0; d >>= 1) s += __shfl_xor(s, d, 32);
                if ((t - 1) >= 1) r_acc += e / s;    // WARMUP=0: accumulate for s>=1
            }
        }

        // ---- 5. branch/soma update + spike bitmask write + arrive ----
        if (doUpd) {
            const float* cl = &curL[r * 36 + nq * 8];
            #pragma unroll
            for (int m = 0; m < 2; ++m) {
                float l_in = 0.f;
                #pragma unroll
                for (int j = 0; j < 4; ++j) {
                    float rc  = (m == 0) ? rec0[j] : rec1[j];
                    float cur = cl[m * 4 + j] + rc + bias[m * 4 + j];
                    float d   = beta[m * 4 + j] * dn[m * 4 + j] + (1.0f - beta[m * 4 + j]) * cur;
                    dn[m * 4 + j] = d;
                    l_in += d;
                }
                float mm = alph[m] * mem[m] + (1.0f - alph[m]) * l_in - spkf[m];  // VTH=1, soft reset
                mem[m]  = mm;
                spkf[m] = (mm > 1.0f) ? 1.0f : 0.0f;   // spike_fn(mem - VTH)
            }
            unsigned s0  = (spkf[0] != 0.f) ? 1u : 0u;
            unsigned s1  = (spkf[1] != 0.f) ? 2u : 0u;
            unsigned nib = (s0 | s1) << (2 * nq);
            nib |= (unsigned)__shfl_xor((int)nib, 1);
            nib |= (unsigned)__shfl_xor((int)nib, 2);
            if (nq == 0)
                ((uint8_t*)masks)[((size_t)(t & 1)) * 16384 + (size_t)b * 128 + w] = (uint8_t)nib;

            __threadfence();
            __syncthreads();
            if (tid == 0)
                __hip_atomic_fetch_add(cnt, 1u, __ATOMIC_RELEASE, __HIP_MEMORY_SCOPE_AGENT);
        }
    }

    if (isRO && tid < OUTD) out[wg * OUTD + tid] = r_acc;
}

extern "C" void kernel_launch(void* const* d_in, const int* in_sizes, int n_in,
                              void* d_out, int out_size, void* d_ws, size_t ws_size,
                              hipStream_t stream) {
    (void)in_sizes; (void)n_in; (void)out_size; (void)ws_size;
    const float* x     = (const float*)d_in[0];
    const float* W     = (const float*)d_in[1];
    const float* bv    = (const float*)d_in[2];
    const float* tau_m = (const float*)d_in[3];
    const float* tau_n = (const float*)d_in[4];
    const float* Wr    = (const float*)d_in[5];
    const float* br    = (const float*)d_in[6];
    const float* tau_r = (const float*)d_in[7];
    const float* mem0  = (const float*)d_in[8];

    char* ws = (char*)d_ws;
    unsigned*        cnt   = (unsigned*)(ws + O_CNT);
    uint64_t*        masks = (uint64_t*)(ws + O_MASK);
    float*           Wst   = (float*)(ws + O_WST);
    __hip_bfloat16*  Wxh   = (__hip_bfloat16*)(ws + O_WXH);
    __hip_bfloat16*  Xh    = (__hip_bfloat16*)(ws + O_XH);

    prep_x<<<2048, 256, 0, stream>>>(x, Xh);
    prep_w<<<2048, 256, 0, stream>>>(W, Wxh, cnt);
    dim3 g3(32, 128), b3(32, 8);
    prep_t<<<g3, b3, 0, stream>>>(W, Wst);
    snn_scan<<<NWG, WGT, 0, stream>>>(Xh, Wxh, Wst, masks, cnt,
                                      bv, tau_m, tau_n, Wr, br, tau_r, mem0, (float*)d_out);
}

// Round 2
// 4064.050 us; speedup vs baseline: 3.1385x; 3.1385x over previous
//
#include <hip/hip_runtime.h>
#include <hip/hip_bf16.h>
#include <stdint.h>

// DH-SNN forward: fused persistent-scan implementation.
// Phase 0 (parallel prep): x -> bf16 [T][B][704]; Wx -> bf16 [4096][704]; Ws^T -> f32 [1024][4096].
// Phase 1 (persistent, 256 WGs = 1/CU): per step t:
//   MFMA x_t @ Wx^T (overlapped with grid barrier wait) + exact fp32 spike-gather of Ws^T rows
//   -> branch/soma update in registers -> spike bitmask exchange -> readout+softmax in wave0 regs.
// Barrier: per-WG release flags + vectorized polling (no single-counter RMW serialization).

typedef short short8 __attribute__((ext_vector_type(8)));
typedef float f32x4 __attribute__((ext_vector_type(4)));

#define T_STEPS 250
#define BATCH   128
#define HID     1024
#define NCOL    4096      // HID*BRANCH
#define IND     700
#define ISZ     1724
#define KPAD    704
#define OUTD    20
#define NWG     256
#define WGT     256

// ws layout (bytes)
#define O_FLAGS 0                // u32[256] = 1024 B
#define O_MASK  1024             // uint64[2][128][16] = 32768 B
#define O_WST   33792            // f32 [1024][4096] = 16777216 B
#define O_WXH   16811008         // bf16 [4096][704] = 5767168 B
#define O_XH    22578176         // bf16 [250][128][704] = 45056000 B  (end ~67.6 MB)

#define AGENT __HIP_MEMORY_SCOPE_AGENT

__device__ __forceinline__ float sigmoidf(float x) { return 1.0f / (1.0f + expf(-x)); }

__global__ void prep_x(const float* __restrict__ x, __hip_bfloat16* __restrict__ Xh) {
    const int total = T_STEPS * BATCH * KPAD;
    for (int idx = blockIdx.x * blockDim.x + threadIdx.x; idx < total; idx += gridDim.x * blockDim.x) {
        int k = idx % KPAD;
        int tb = idx / KPAD;
        int b = tb % BATCH;
        int t = tb / BATCH;
        float v = (k < IND) ? x[((long)b * T_STEPS + t) * IND + k] : 0.0f;
        Xh[idx] = __float2bfloat16(v);
    }
}

__global__ void prep_w(const float* __restrict__ W, __hip_bfloat16* __restrict__ Wxh,
                       unsigned* __restrict__ flags) {
    if (blockIdx.x == 0 && threadIdx.x < NWG)   // reset barrier flags every launch (graph replay!)
        __hip_atomic_store(&flags[threadIdx.x], 0u, __ATOMIC_RELAXED, AGENT);
    const int total = NCOL * KPAD;
    for (int idx = blockIdx.x * blockDim.x + threadIdx.x; idx < total; idx += gridDim.x * blockDim.x) {
        int k = idx % KPAD;
        int n = idx / KPAD;
        float v = (k < IND) ? W[(long)n * ISZ + k] : 0.0f;
        Wxh[idx] = __float2bfloat16(v);
    }
}

// Wst[h][n] = W[n][700+h]   (tiled transpose)
__global__ __launch_bounds__(256) void prep_t(const float* __restrict__ W, float* __restrict__ Wst) {
    __shared__ float tile[32][33];
    const int h0 = blockIdx.x * 32, n0 = blockIdx.y * 32;
    const int tx = threadIdx.x, ty = threadIdx.y;  // (32,8)
    #pragma unroll
    for (int j = 0; j < 32; j += 8)
        tile[ty + j][tx] = W[(long)(n0 + ty + j) * ISZ + IND + h0 + tx];
    __syncthreads();
    #pragma unroll
    for (int j = 0; j < 32; j += 8)
        Wst[(long)(h0 + ty + j) * NCOL + n0 + tx] = tile[tx][ty + j];
}

__global__ __launch_bounds__(256, 1) void snn_scan(
    const __hip_bfloat16* __restrict__ Xh, const __hip_bfloat16* __restrict__ Wxh,
    const float* __restrict__ Wst, uint64_t* __restrict__ masks, unsigned* __restrict__ flags,
    const float* __restrict__ bvec, const float* __restrict__ tau_m, const float* __restrict__ tau_n,
    const float* __restrict__ Wr, const float* __restrict__ brv, const float* __restrict__ tau_r,
    const float* __restrict__ mem0, float* __restrict__ out)
{
    __shared__ __hip_bfloat16 Bp[32 * 712];   // Wx^T panel: [32 cols][704 k]
    __shared__ float curL[64 * 36];           // C exchange [64 rows][32 cols], pad 36
    __shared__ uint64_t mLds[64 * 17];        // staged spike masks (own batch half), pad 17
    __shared__ uint64_t roMask[16];           // readout-row mask snapshot

    const int wg    = blockIdx.x;     // 0..255
    const int w     = wg & 127;       // column group: cols [w*32, w*32+32) = neurons [w*8, w*8+8)
    const int bhalf = wg >> 7;        // row split: batches [0,64) or [64,128)
    const int bbase = bhalf * 64;
    const int c0    = w * 32;
    const int i0    = w * 8;
    const int tid   = threadIdx.x;
    const int lane  = tid & 63, wid = tid >> 6;

    // stage B panel into LDS (persistent for all 250 steps)
    for (int idx = tid; idx < 32 * KPAD; idx += WGT) {
        int col = idx / KPAD, k = idx % KPAD;
        Bp[col * 712 + k] = Wxh[(long)(c0 + col) * KPAD + k];
    }

    // per-thread state: 2 neurons x 4 branches, one batch row
    const int r  = tid >> 2;          // local batch row 0..63
    const int nq = tid & 3;
    const int b  = bbase + r;         // global batch
    float dn[8], beta[8], bias[8], mem[2], alph[2], spkf[2];
    #pragma unroll
    for (int m = 0; m < 2; ++m) {
        int i = i0 + nq * 2 + m;
        alph[m] = sigmoidf(tau_m[i]);
        mem[m]  = mem0[b * HID + i];
        spkf[m] = 0.0f;
        #pragma unroll
        for (int j = 0; j < 4; ++j) {
            beta[m * 4 + j] = sigmoidf(tau_n[i * 4 + j]);
            bias[m * 4 + j] = bvec[i * 4 + j];
            dn[m * 4 + j]   = 0.0f;
        }
    }

    // readout state (WG b<128 handles batch wg; lanes 0..19 of wave 0)
    const bool isRO = (wg < BATCH) && (tid < 32);
    float r_alpha = 0.f, r_bias = 0.f, r_rmem = 0.f, r_acc = 0.f;
    const float* WrRow = Wr;
    if (isRO) {
        int o = (tid < OUTD) ? tid : 0;
        r_alpha = sigmoidf(tau_r[o]);
        r_bias  = brv[o];
        WrRow   = Wr + o * HID;
    }

    // GEMM addressing
    const int arowL = wid * 16 + (lane & 15);    // local output row 0..63
    const int kb8   = (lane >> 4) * 8;           // k-subblock within K=32 step
    const int colA  = lane & 15;                 // fragment column
    const __hip_bfloat16* Arow = Xh + ((long)bbase + arowL) * KPAD + kb8;

    __syncthreads();

    for (int t = 0; t <= T_STEPS; ++t) {
        const bool doUpd = (t < T_STEPS);
        f32x4 acc0 = {0.f, 0.f, 0.f, 0.f}, acc1 = {0.f, 0.f, 0.f, 0.f};

        // ---- 1. MFMA x_t @ Wx^T (issued BEFORE the barrier wait -> overlaps spin) ----
        if (doUpd) {
            const __hip_bfloat16* Ab = Arow + (long)t * BATCH * KPAD;
            #pragma unroll
            for (int k0 = 0; k0 < KPAD; k0 += 32) {
                short8 af = *(const short8*)(Ab + k0);
                short8 b0 = *(const short8*)(&Bp[(colA) * 712 + k0 + kb8]);
                short8 b1 = *(const short8*)(&Bp[(16 + colA) * 712 + k0 + kb8]);
                acc0 = __builtin_amdgcn_mfma_f32_16x16x32_bf16(af, b0, acc0, 0, 0, 0);
                acc1 = __builtin_amdgcn_mfma_f32_16x16x32_bf16(af, b1, acc1, 0, 0, 0);
            }
        }

        // ---- 2. wait: spikes[t-1] globally visible (flag barrier, no RMW) ----
        if (t > 0) {
            const unsigned target = (unsigned)t;
            if (wid == 0) {
                const unsigned* f = flags + lane * 4;
                for (;;) {
                    unsigned a0 = __hip_atomic_load(f + 0, __ATOMIC_RELAXED, AGENT);
                    unsigned a1 = __hip_atomic_load(f + 1, __ATOMIC_RELAXED, AGENT);
                    unsigned a2 = __hip_atomic_load(f + 2, __ATOMIC_RELAXED, AGENT);
                    unsigned a3 = __hip_atomic_load(f + 3, __ATOMIC_RELAXED, AGENT);
                    bool ok = (a0 >= target) & (a1 >= target) & (a2 >= target) & (a3 >= target);
                    if (__all(ok)) break;
                    __builtin_amdgcn_s_sleep(1);
                }
            }
            __syncthreads();
            __builtin_amdgcn_fence(__ATOMIC_ACQUIRE, "agent");
        }

        // ---- 3. stage masks[t-1] (own batch half) into LDS + readout snapshot ----
        if (t > 0) {
            if (doUpd) {
                const uint64_t* src = masks + ((size_t)((t - 1) & 1)) * 2048
                                      + (size_t)(bbase + (tid >> 2)) * 16 + (size_t)(tid & 3) * 4;
                uint64_t v0 = __hip_atomic_load(src + 0, __ATOMIC_RELAXED, AGENT);
                uint64_t v1 = __hip_atomic_load(src + 1, __ATOMIC_RELAXED, AGENT);
                uint64_t v2 = __hip_atomic_load(src + 2, __ATOMIC_RELAXED, AGENT);
                uint64_t v3 = __hip_atomic_load(src + 3, __ATOMIC_RELAXED, AGENT);
                uint64_t* dst = &mLds[(tid >> 2) * 17 + (tid & 3) * 4];
                dst[0] = v0; dst[1] = v1; dst[2] = v2; dst[3] = v3;
            }
            if (wg < BATCH && tid < 16)
                roMask[tid] = __hip_atomic_load(
                    masks + ((size_t)((t - 1) & 1)) * 2048 + (size_t)wg * 16 + tid,
                    __ATOMIC_RELAXED, AGENT);
        }

        // ---- 4. C fragments -> LDS (also publishes mLds via the same barrier) ----
        if (doUpd) {
            const int crow = wid * 16 + (lane >> 4) * 4;
            #pragma unroll
            for (int j = 0; j < 4; ++j) {
                curL[(crow + j) * 36 + colA]      = acc0[j];
                curL[(crow + j) * 36 + 16 + colA] = acc1[j];
            }
            __syncthreads();
        }

        // ---- 5. recurrent gather (exact fp32) from LDS-staged masks ----
        f32x4 rec0 = {0.f, 0.f, 0.f, 0.f}, rec1 = {0.f, 0.f, 0.f, 0.f};
        if (t > 0 && doUpd) {
            const float* Wb = Wst + c0 + nq * 8;
            #pragma unroll 4
            for (int q = 0; q < 16; ++q) {
                uint64_t mword = mLds[r * 17 + q];
                while (mword) {
                    int h = (q << 6) + __builtin_ctzll(mword);
                    mword &= mword - 1;
                    const f32x4* wv = (const f32x4*)(Wb + (long)h * NCOL);
                    rec0 += wv[0];
                    rec1 += wv[1];
                }
            }
        }

        // ---- 6. branch/soma update + spike bitmask write + release ----
        if (doUpd) {
            const float* cl = &curL[r * 36 + nq * 8];
            #pragma unroll
            for (int m = 0; m < 2; ++m) {
                float l_in = 0.f;
                #pragma unroll
                for (int j = 0; j < 4; ++j) {
                    float rc  = (m == 0) ? rec0[j] : rec1[j];
                    float cur = cl[m * 4 + j] + rc + bias[m * 4 + j];
                    float d   = beta[m * 4 + j] * dn[m * 4 + j] + (1.0f - beta[m * 4 + j]) * cur;
                    dn[m * 4 + j] = d;
                    l_in += d;
                }
                float mm = alph[m] * mem[m] + (1.0f - alph[m]) * l_in - spkf[m];  // VTH=1, soft reset
                mem[m]  = mm;
                spkf[m] = (mm > 1.0f) ? 1.0f : 0.0f;   // spike_fn(mem - VTH)
            }
            unsigned s0  = (spkf[0] != 0.f) ? 1u : 0u;
            unsigned s1  = (spkf[1] != 0.f) ? 2u : 0u;
            unsigned nib = (s0 | s1) << (2 * nq);
            nib |= (unsigned)__shfl_xor((int)nib, 1);
            nib |= (unsigned)__shfl_xor((int)nib, 2);
            if (nq == 0)
                __hip_atomic_store(
                    (uint8_t*)masks + ((size_t)(t & 1)) * 16384 + (size_t)b * 128 + w,
                    (uint8_t)nib, __ATOMIC_RELAXED, AGENT);

            __syncthreads();   // drains every wave's mask stores (vmcnt(0) before s_barrier)
            if (tid == 0)
                __hip_atomic_store(&flags[wg], (unsigned)(t + 1), __ATOMIC_RELEASE, AGENT);
        }

        // ---- 7. readout + softmax for step t-1 (off critical path, uses LDS snapshot) ----
        if (t > 0 && isRO) {
            float rsum = 0.f;
            for (int q = 0; q < 16; ++q) {
                uint64_t mword = roMask[q];
                while (mword) {
                    int h = (q << 6) + __builtin_ctzll(mword);
                    mword &= mword - 1;
                    rsum += WrRow[h];
                }
            }
            r_rmem = r_alpha * r_rmem + (1.0f - r_alpha) * (rsum + r_bias);
            float v = (tid < OUTD) ? r_rmem : -__builtin_inff();
            #pragma unroll
            for (int d = 16; d > 0; d >>= 1) v = fmaxf(v, __shfl_xor(v, d, 32));
            float e = (tid < OUTD) ? expf(r_rmem - v) : 0.f;
            float s = e;
            #pragma unroll
            for (int d = 16; d > 0; d >>= 1) s += __shfl_xor(s, d, 32);
            if ((t - 1) >= 1) r_acc += e / s;    // WARMUP=0: accumulate for s>=1
        }
    }

    if (isRO && tid < OUTD) out[wg * OUTD + tid] = r_acc;
}

extern "C" void kernel_launch(void* const* d_in, const int* in_sizes, int n_in,
                              void* d_out, int out_size, void* d_ws, size_t ws_size,
                              hipStream_t stream) {
    (void)in_sizes; (void)n_in; (void)out_size; (void)ws_size;
    const float* x     = (const float*)d_in[0];
    const float* W     = (const float*)d_in[1];
    const float* bv    = (const float*)d_in[2];
    const float* tau_m = (const float*)d_in[3];
    const float* tau_n = (const float*)d_in[4];
    const float* Wr    = (const float*)d_in[5];
    const float* br    = (const float*)d_in[6];
    const float* tau_r = (const float*)d_in[7];
    const float* mem0  = (const float*)d_in[8];

    char* ws = (char*)d_ws;
    unsigned*        flags = (unsigned*)(ws + O_FLAGS);
    uint64_t*        masks = (uint64_t*)(ws + O_MASK);
    float*           Wst   = (float*)(ws + O_WST);
    __hip_bfloat16*  Wxh   = (__hip_bfloat16*)(ws + O_WXH);
    __hip_bfloat16*  Xh    = (__hip_bfloat16*)(ws + O_XH);

    prep_x<<<2048, 256, 0, stream>>>(x, Xh);
    prep_w<<<2048, 256, 0, stream>>>(W, Wxh, flags);
    dim3 g3(32, 128), b3(32, 8);
    prep_t<<<g3, b3, 0, stream>>>(W, Wst);
    snn_scan<<<NWG, WGT, 0, stream>>>(Xh, Wxh, Wst, masks, flags,
                                      bv, tau_m, tau_n, Wr, br, tau_r, mem0, (float*)d_out);
}

// Round 3
// 1803.108 us; speedup vs baseline: 7.0739x; 2.2539x over previous
//
#include <hip/hip_runtime.h>
#include <hip/hip_bf16.h>
#include <stdint.h>

// DH-SNN forward: fused persistent-scan implementation.
// Phase 0 (parallel prep): x -> bf16 [T][B][704]; Wx -> bf16 [4096][704]; Ws^T -> f32 [1024][4096].
// Phase 1 (persistent, 256 WGs = 1/CU): per step t:
//   MFMA x_t @ Wx^T (overlapped with barrier wait) + exact fp32 spike-gather of Ws^T rows
//   -> branch/soma update in registers -> spike bitmask exchange -> readout+softmax in wave0 regs.
// Barrier: two independent 128-WG half-barriers, two-level (producer flags -> aggregator ->
// replicated epoch lines), all relaxed agent-scope atomics, ZERO fences (no wbl2/inv).

typedef short short8 __attribute__((ext_vector_type(8)));
typedef float f32x4 __attribute__((ext_vector_type(4)));

#define T_STEPS 250
#define BATCH   128
#define HID     1024
#define NCOL    4096      // HID*BRANCH
#define IND     700
#define ISZ     1724
#define KPAD    704
#define OUTD    20
#define NWG     256
#define WGT     256

// ws layout (bytes)
#define O_FLAGS 0                // u32[256] = 1024 B
#define O_EPOCH 1024             // u32[2][8][32] (8 copies/half, 128B apart) = 2048 B
#define O_MASK  4096             // uint64[2][128][16] = 32768 B
#define O_WST   36864            // f32 [1024][4096] = 16777216 B
#define O_WXH   16814080         // bf16 [4096][704] = 5767168 B
#define O_XH    22581248         // bf16 [250][128][704] = 45056000 B  (end ~64.5 MB)

#define AGENT __HIP_MEMORY_SCOPE_AGENT

__device__ __forceinline__ float sigmoidf(float x) { return 1.0f / (1.0f + expf(-x)); }

__global__ void prep_x(const float* __restrict__ x, __hip_bfloat16* __restrict__ Xh) {
    const int total = T_STEPS * BATCH * KPAD;
    for (int idx = blockIdx.x * blockDim.x + threadIdx.x; idx < total; idx += gridDim.x * blockDim.x) {
        int k = idx % KPAD;
        int tb = idx / KPAD;
        int b = tb % BATCH;
        int t = tb / BATCH;
        float v = (k < IND) ? x[((long)b * T_STEPS + t) * IND + k] : 0.0f;
        Xh[idx] = __float2bfloat16(v);
    }
}

__global__ void prep_w(const float* __restrict__ W, __hip_bfloat16* __restrict__ Wxh,
                       unsigned* __restrict__ flags, unsigned* __restrict__ epochs) {
    if (blockIdx.x == 0) {       // reset barrier state every launch (graph replay!)
        if (threadIdx.x < NWG)
            __hip_atomic_store(&flags[threadIdx.x], 0u, __ATOMIC_RELAXED, AGENT);
        for (int idx = threadIdx.x; idx < 2 * 8 * 32; idx += blockDim.x)
            __hip_atomic_store(&epochs[idx], 0u, __ATOMIC_RELAXED, AGENT);
    }
    const int total = NCOL * KPAD;
    for (int idx = blockIdx.x * blockDim.x + threadIdx.x; idx < total; idx += gridDim.x * blockDim.x) {
        int k = idx % KPAD;
        int n = idx / KPAD;
        float v = (k < IND) ? W[(long)n * ISZ + k] : 0.0f;
        Wxh[idx] = __float2bfloat16(v);
    }
}

// Wst[h][n] = W[n][700+h]   (tiled transpose)
__global__ __launch_bounds__(256) void prep_t(const float* __restrict__ W, float* __restrict__ Wst) {
    __shared__ float tile[32][33];
    const int h0 = blockIdx.x * 32, n0 = blockIdx.y * 32;
    const int tx = threadIdx.x, ty = threadIdx.y;  // (32,8)
    #pragma unroll
    for (int j = 0; j < 32; j += 8)
        tile[ty + j][tx] = W[(long)(n0 + ty + j) * ISZ + IND + h0 + tx];
    __syncthreads();
    #pragma unroll
    for (int j = 0; j < 32; j += 8)
        Wst[(long)(h0 + ty + j) * NCOL + n0 + tx] = tile[tx][ty + j];
}

__global__ __launch_bounds__(256, 1) void snn_scan(
    const __hip_bfloat16* __restrict__ Xh, const __hip_bfloat16* __restrict__ Wxh,
    const float* __restrict__ Wst, uint64_t* __restrict__ masks, unsigned* __restrict__ flags,
    unsigned* __restrict__ epochs,
    const float* __restrict__ bvec, const float* __restrict__ tau_m, const float* __restrict__ tau_n,
    const float* __restrict__ Wr, const float* __restrict__ brv, const float* __restrict__ tau_r,
    const float* __restrict__ mem0, float* __restrict__ out)
{
    __shared__ __hip_bfloat16 Bp[32 * 712];   // Wx^T panel: [32 cols][704 k]
    __shared__ float curL[64 * 36];           // C exchange [64 rows][32 cols], pad 36
    __shared__ uint64_t mLds[64 * 17];        // staged spike masks (own batch half), pad 17
    __shared__ uint64_t roMask[16];           // readout-row mask snapshot

    const int wg    = blockIdx.x;     // 0..255
    const int w     = wg & 127;       // column group: cols [w*32, w*32+32) = neurons [w*8, w*8+8)
    const int bhalf = wg >> 7;        // row split: batches [0,64) or [64,128)
    const int bbase = bhalf * 64;
    const int c0    = w * 32;
    const int i0    = w * 8;
    const int tid   = threadIdx.x;
    const int lane  = tid & 63, wid = tid >> 6;
    const int halfbase = bhalf << 7;
    const bool isAgg = (w == 0);      // wg 0 and wg 128 aggregate their half

    // stage B panel into LDS (persistent for all 250 steps)
    for (int idx = tid; idx < 32 * KPAD; idx += WGT) {
        int col = idx / KPAD, k = idx % KPAD;
        Bp[col * 712 + k] = Wxh[(long)(c0 + col) * KPAD + k];
    }

    // per-thread state: 2 neurons x 4 branches, one batch row
    const int r  = tid >> 2;          // local batch row 0..63
    const int nq = tid & 3;
    const int b  = bbase + r;         // global batch
    float dn[8], beta[8], bias[8], mem[2], alph[2], spkf[2];
    #pragma unroll
    for (int m = 0; m < 2; ++m) {
        int i = i0 + nq * 2 + m;
        alph[m] = sigmoidf(tau_m[i]);
        mem[m]  = mem0[b * HID + i];
        spkf[m] = 0.0f;
        #pragma unroll
        for (int j = 0; j < 4; ++j) {
            beta[m * 4 + j] = sigmoidf(tau_n[i * 4 + j]);
            bias[m * 4 + j] = bvec[i * 4 + j];
            dn[m * 4 + j]   = 0.0f;
        }
    }

    // readout: row roB handled by a WG of the SAME batch half (half-barrier sufficiency):
    // rows 0..63 -> wg 0..63; rows 64..127 -> wg 128..191.
    const int roB = (wg < 64) ? wg : ((wg >= 128 && wg < 192) ? wg - 64 : -1);
    const bool isRO = (roB >= 0) && (tid < 32);
    float r_alpha = 0.f, r_bias = 0.f, r_rmem = 0.f, r_acc = 0.f;
    const float* WrRow = Wr;
    if (isRO) {
        int o = (tid < OUTD) ? tid : 0;
        r_alpha = sigmoidf(tau_r[o]);
        r_bias  = brv[o];
        WrRow   = Wr + o * HID;
    }

    // GEMM addressing
    const int arowL = wid * 16 + (lane & 15);    // local output row 0..63
    const int kb8   = (lane >> 4) * 8;           // k-subblock within K=32 step
    const int colA  = lane & 15;                 // fragment column
    const __hip_bfloat16* Arow = Xh + ((long)bbase + arowL) * KPAD + kb8;

    // epoch copy this WG polls (spread over 8 lines per half)
    unsigned* epAddr = epochs + ((size_t)bhalf * 8 + (size_t)(wg & 7)) * 32;

    __syncthreads();

    for (int t = 0; t <= T_STEPS; ++t) {
        const bool doUpd = (t < T_STEPS);
        f32x4 acc0 = {0.f, 0.f, 0.f, 0.f}, acc1 = {0.f, 0.f, 0.f, 0.f};

        // ---- 1. MFMA x_t @ Wx^T (issued BEFORE the barrier wait -> overlaps spin) ----
        if (doUpd) {
            const __hip_bfloat16* Ab = Arow + (long)t * BATCH * KPAD;
            #pragma unroll
            for (int k0 = 0; k0 < KPAD; k0 += 32) {
                short8 af = *(const short8*)(Ab + k0);
                short8 b0 = *(const short8*)(&Bp[(colA) * 712 + k0 + kb8]);
                short8 b1 = *(const short8*)(&Bp[(16 + colA) * 712 + k0 + kb8]);
                acc0 = __builtin_amdgcn_mfma_f32_16x16x32_bf16(af, b0, acc0, 0, 0, 0);
                acc1 = __builtin_amdgcn_mfma_f32_16x16x32_bf16(af, b1, acc1, 0, 0, 0);
            }
        }

        // ---- 2. wait: spikes[t-1] of own half visible ----
        if (t > 0) {
            const unsigned target = (unsigned)t;
            if (isAgg) {
                // aggregator: wave 0 polls the 128 producer flags of this half (2/lane)
                if (wid == 0) {
                    const unsigned* f = flags + halfbase + lane * 2;
                    for (;;) {
                        unsigned a0 = __hip_atomic_load(f + 0, __ATOMIC_RELAXED, AGENT);
                        unsigned a1 = __hip_atomic_load(f + 1, __ATOMIC_RELAXED, AGENT);
                        if (__all((a0 >= target) & (a1 >= target))) break;
                        __builtin_amdgcn_s_sleep(1);
                    }
                    if (lane < 8)
                        __hip_atomic_store(epochs + ((size_t)bhalf * 8 + lane) * 32, target,
                                           __ATOMIC_RELAXED, AGENT);
                }
            } else {
                if (tid == 0) {
                    while (__hip_atomic_load(epAddr, __ATOMIC_RELAXED, AGENT) < target)
                        __builtin_amdgcn_s_sleep(1);
                }
            }
            __syncthreads();
        }

        // ---- 3. stage masks[t-1] (own batch half) into LDS + readout snapshot ----
        if (t > 0) {
            if (doUpd) {
                const uint64_t* src = masks + ((size_t)((t - 1) & 1)) * 2048
                                      + (size_t)(bbase + (tid >> 2)) * 16 + (size_t)(tid & 3) * 4;
                uint64_t v0 = __hip_atomic_load(src + 0, __ATOMIC_RELAXED, AGENT);
                uint64_t v1 = __hip_atomic_load(src + 1, __ATOMIC_RELAXED, AGENT);
                uint64_t v2 = __hip_atomic_load(src + 2, __ATOMIC_RELAXED, AGENT);
                uint64_t v3 = __hip_atomic_load(src + 3, __ATOMIC_RELAXED, AGENT);
                uint64_t* dst = &mLds[(tid >> 2) * 17 + (tid & 3) * 4];
                dst[0] = v0; dst[1] = v1; dst[2] = v2; dst[3] = v3;
            }
            if (roB >= 0 && tid < 16)
                roMask[tid] = __hip_atomic_load(
                    masks + ((size_t)((t - 1) & 1)) * 2048 + (size_t)roB * 16 + tid,
                    __ATOMIC_RELAXED, AGENT);
        }

        // ---- 4. C fragments -> LDS (also publishes mLds/roMask via the same barrier) ----
        if (doUpd) {
            const int crow = wid * 16 + (lane >> 4) * 4;
            #pragma unroll
            for (int j = 0; j < 4; ++j) {
                curL[(crow + j) * 36 + colA]      = acc0[j];
                curL[(crow + j) * 36 + 16 + colA] = acc1[j];
            }
            __syncthreads();
        }

        // ---- 5. recurrent gather (exact fp32) from LDS-staged masks ----
        f32x4 rec0 = {0.f, 0.f, 0.f, 0.f}, rec1 = {0.f, 0.f, 0.f, 0.f};
        if (t > 0 && doUpd) {
            const float* Wb = Wst + c0 + nq * 8;
            #pragma unroll 4
            for (int q = 0; q < 16; ++q) {
                uint64_t mword = mLds[r * 17 + q];
                while (mword) {
                    int h = (q << 6) + __builtin_ctzll(mword);
                    mword &= mword - 1;
                    const f32x4* wv = (const f32x4*)(Wb + (long)h * NCOL);
                    rec0 += wv[0];
                    rec1 += wv[1];
                }
            }
        }

        // ---- 6. branch/soma update + spike bitmask write + relaxed flag release ----
        if (doUpd) {
            const float* cl = &curL[r * 36 + nq * 8];
            #pragma unroll
            for (int m = 0; m < 2; ++m) {
                float l_in = 0.f;
                #pragma unroll
                for (int j = 0; j < 4; ++j) {
                    float rc  = (m == 0) ? rec0[j] : rec1[j];
                    float cur = cl[m * 4 + j] + rc + bias[m * 4 + j];
                    float d   = beta[m * 4 + j] * dn[m * 4 + j] + (1.0f - beta[m * 4 + j]) * cur;
                    dn[m * 4 + j] = d;
                    l_in += d;
                }
                float mm = alph[m] * mem[m] + (1.0f - alph[m]) * l_in - spkf[m];  // VTH=1, soft reset
                mem[m]  = mm;
                spkf[m] = (mm > 1.0f) ? 1.0f : 0.0f;   // spike_fn(mem - VTH)
            }
            unsigned s0  = (spkf[0] != 0.f) ? 1u : 0u;
            unsigned s1  = (spkf[1] != 0.f) ? 2u : 0u;
            unsigned nib = (s0 | s1) << (2 * nq);
            nib |= (unsigned)__shfl_xor((int)nib, 1);
            nib |= (unsigned)__shfl_xor((int)nib, 2);
            if (nq == 0)
                __hip_atomic_store(
                    (uint8_t*)masks + ((size_t)(t & 1)) * 16384 + (size_t)b * 128 + w,
                    (uint8_t)nib, __ATOMIC_RELAXED, AGENT);

            // drain this wave's mask store, then barrier => all waves' stores at coherence point
            asm volatile("s_waitcnt vmcnt(0)" ::: "memory");
            __syncthreads();
            if (tid == 0)
                __hip_atomic_store(&flags[wg], (unsigned)(t + 1), __ATOMIC_RELAXED, AGENT);
        }

        // ---- 7. readout + softmax for step t-1 (off critical path, uses LDS snapshot) ----
        if (t > 0 && isRO) {
            float rsum = 0.f;
            for (int q = 0; q < 16; ++q) {
                uint64_t mword = roMask[q];
                while (mword) {
                    int h = (q << 6) + __builtin_ctzll(mword);
                    mword &= mword - 1;
                    rsum += WrRow[h];
                }
            }
            r_rmem = r_alpha * r_rmem + (1.0f - r_alpha) * (rsum + r_bias);
            float v = (tid < OUTD) ? r_rmem : -__builtin_inff();
            #pragma unroll
            for (int d = 16; d > 0; d >>= 1) v = fmaxf(v, __shfl_xor(v, d, 32));
            float e = (tid < OUTD) ? expf(r_rmem - v) : 0.f;
            float s = e;
            #pragma unroll
            for (int d = 16; d > 0; d >>= 1) s += __shfl_xor(s, d, 32);
            if ((t - 1) >= 1) r_acc += e / s;    // WARMUP=0: accumulate for s>=1
        }
    }

    if (isRO && tid < OUTD) out[roB * OUTD + tid] = r_acc;
}

extern "C" void kernel_launch(void* const* d_in, const int* in_sizes, int n_in,
                              void* d_out, int out_size, void* d_ws, size_t ws_size,
                              hipStream_t stream) {
    (void)in_sizes; (void)n_in; (void)out_size; (void)ws_size;
    const float* x     = (const float*)d_in[0];
    const float* W     = (const float*)d_in[1];
    const float* bv    = (const float*)d_in[2];
    const float* tau_m = (const float*)d_in[3];
    const float* tau_n = (const float*)d_in[4];
    const float* Wr    = (const float*)d_in[5];
    const float* br    = (const float*)d_in[6];
    const float* tau_r = (const float*)d_in[7];
    const float* mem0  = (const float*)d_in[8];

    char* ws = (char*)d_ws;
    unsigned*        flags  = (unsigned*)(ws + O_FLAGS);
    unsigned*        epochs = (unsigned*)(ws + O_EPOCH);
    uint64_t*        masks  = (uint64_t*)(ws + O_MASK);
    float*           Wst    = (float*)(ws + O_WST);
    __hip_bfloat16*  Wxh    = (__hip_bfloat16*)(ws + O_WXH);
    __hip_bfloat16*  Xh     = (__hip_bfloat16*)(ws + O_XH);

    prep_x<<<2048, 256, 0, stream>>>(x, Xh);
    prep_w<<<2048, 256, 0, stream>>>(W, Wxh, flags, epochs);
    dim3 g3(32, 128), b3(32, 8);
    prep_t<<<g3, b3, 0, stream>>>(W, Wst);
    snn_scan<<<NWG, WGT, 0, stream>>>(Xh, Wxh, Wst, masks, flags, epochs,
                                      bv, tau_m, tau_n, Wr, br, tau_r, mem0, (float*)d_out);
}